// Round 16
// baseline (184.225 us; speedup 1.0000x reference)
//
#include <hip/hip_runtime.h>

typedef __bf16 bf16_t;
typedef __bf16 bf16x8 __attribute__((ext_vector_type(8)));
typedef __bf16 bf16x4 __attribute__((ext_vector_type(4)));
typedef float  f32x4  __attribute__((ext_vector_type(4)));
typedef int    i32x4  __attribute__((ext_vector_type(4)));

#define B_      16
#define L_      2048
#define D_      128
#define QTB     128              // q rows per block = 8 waves x 16
#define NEGINF  (-1.0e9f)
#define SCALE   0.08838834764831845f   // 1/sqrt(128)

#define MFMA_BF16 __builtin_amdgcn_mfma_f32_16x16x32_bf16

// Drain LDS ops before the barrier WITHOUT draining vmcnt.
#define BARRIER() do { asm volatile("s_waitcnt lgkmcnt(0)" ::: "memory"); \
                       __builtin_amdgcn_s_barrier(); } while (0)

// ---------------------------------------------------------------------------
// Prep kernel: blocks 0..255  : V fp32 [B][L][D] -> bf16 VT [B][D][L]
//              blocks 256..511: K fp32 -> bf16 row-major
// ---------------------------------------------------------------------------
__global__ __launch_bounds__(256) void prep_kernel(
    const float* __restrict__ k, const float* __restrict__ v,
    bf16_t* __restrict__ kb, bf16_t* __restrict__ vt)
{
    __shared__ bf16_t tile[128 * 144];
    const int tid = threadIdx.x;
    const int bid = (int)blockIdx.x;

    if (bid < 256) {
        const int b  = bid >> 4;
        const int l0 = (bid & 15) * 128;
        #pragma unroll
        for (int it = 0; it < 16; ++it) {
            int idx = tid + it * 256;
            int row = idx >> 5;
            int dc4 = idx & 31;
            f32x4 x = __builtin_nontemporal_load(
                (const f32x4*)(v + ((size_t)b * L_ + l0 + row) * (size_t)D_ + dc4 * 4));
            #pragma unroll
            for (int i = 0; i < 4; ++i) tile[(dc4 * 4 + i) * 144 + row] = (bf16_t)x[i];
        }
        __syncthreads();
        #pragma unroll
        for (int it = 0; it < 8; ++it) {
            int idx = tid + it * 256;
            int d   = idx >> 4;
            int lc  = idx & 15;
            bf16x8 vec = *(const bf16x8*)&tile[d * 144 + lc * 8];
            *(bf16x8*)(vt + ((size_t)b * D_ + d) * (size_t)L_ + l0 + lc * 8) = vec;
        }
    } else {
        const int idx0 = (bid - 256) * 256 + tid;
        #pragma unroll
        for (int c = 0; c < 16; ++c) {
            int idx = idx0 + c * 65536;
            f32x4 x = __builtin_nontemporal_load((const f32x4*)(k + (size_t)idx * 4));
            bf16x4 o;
            #pragma unroll
            for (int i = 0; i < 4; ++i) o[i] = (bf16_t)x[i];
            *(bf16x4*)(kb + (size_t)idx * 4) = o;
        }
    }
}

// ---------------------------------------------------------------------------
// Main kernel: 256 blocks (1/CU), 8 waves, 128 q-rows per block.
// Pass 1: macro-chunk = 128 k-cols (4 subs), 16 barriers; mask loaded
//         per-consumer-lane straight to registers (distance-2 A/B sets);
//         K via frag-order LDS slabs (2 x 32KB in Kbig).
// Pass 2: r15 verbatim (macro = 64, 2-slab, distance-2 reg sets), K slabs
//         re-based into Kbig (2 x 16KB), V slabs in Vbuf (2 x 16KB).
// ---------------------------------------------------------------------------
template <bool WS>
__global__ __launch_bounds__(512, 1) void sdpa_kernel(
    const float* __restrict__ q, const float* __restrict__ k,
    const float* __restrict__ v, const int* __restrict__ mask,
    const bf16_t* __restrict__ kb, const bf16_t* __restrict__ vt,
    float* __restrict__ out, float* __restrict__ attn)
{
    __shared__ char     Kbig[65536];       // p1: 2 slabs x 4 subs x 8K; p2: 2 x 2 x 8K
    __shared__ char     Vbuf[32768];       // p2: 2 slabs x 2 subs x 8K (frag order)
    __shared__ unsigned mlds[8 * 1024];    // 32KB packed mask bits (per-wave regions)
    __shared__ bf16_t   plds[8][16][40];   // 10KB P bounce (per-wave)

    const int tid = threadIdx.x;
    const int w   = tid >> 6;
    const int l   = tid & 63;
    const int li  = l & 15;
    const int lg  = l >> 4;

    // XCD-chunked bijective swizzle (256 % 8 == 0): 2 whole batches per XCD
    const int bid  = (int)blockIdx.x;
    const int bid2 = (bid & 7) * 32 + (bid >> 3);
    const int b    = bid2 >> 4;
    const int qt   = bid2 & 15;
    const int qbase = qt * QTB;

    const size_t bq = (size_t)b * L_;

    const float*  qp  = q  + (bq + qbase) * (size_t)D_;
    const bf16_t* kbp = kb + bq * (size_t)D_;
    const float*  kp  = k  + bq * (size_t)D_;
    const bf16_t* vtp = vt + (size_t)b * D_ * (size_t)L_;
    const float*  vp  = v  + bq * (size_t)D_;
    float* attnrow = attn + (bq + qbase + (size_t)(w * 16 + li)) * (size_t)L_;
    float* outp    = out  + (bq + qbase) * (size_t)D_;

    // ---------------- Q B-fragments (pre-scaled by 1/temper)
    bf16x8 aq[4];
    #pragma unroll
    for (int ds = 0; ds < 4; ++ds) {
        const float* p = qp + (size_t)(w * 16 + li) * D_ + ds * 32 + lg * 8;
        f32x4 x0 = *(const f32x4*)p;
        f32x4 x1 = *(const f32x4*)(p + 4);
        bf16x8 a;
        #pragma unroll
        for (int u = 0; u < 4; ++u) {
            a[u]     = (bf16_t)(x0[u] * SCALE);
            a[4 + u] = (bf16_t)(x1[u] * SCALE);
        }
        aq[ds] = a;
    }

    // ---------------- K staging: fragment order, identity unit (LDS at tid*16)
    const int ku_t  = (tid >> 6) & 1;
    const int ku_lg = (tid >> 4) & 3;
    const int ku_li = tid & 15;
    const int ku_ds = tid >> 7;
    const bf16_t* ksrcb = kbp + (size_t)(ku_t * 16 + ku_li) * D_ + ku_ds * 32 + ku_lg * 8;
    const float*  ksrcf = kp  + (size_t)(ku_t * 16 + ku_li) * D_ + ku_ds * 32 + ku_lg * 8;

    // ---------------- V staging: fragment order, identity unit (pass 2)
    const int vu_d  = ((tid >> 6) << 4) | (tid & 15);
    const int vu_lg = (tid >> 4) & 3;
    const bf16_t* vsrcb = vtp + (size_t)vu_d * L_ + vu_lg * 8;

    // ---------------- mask: per-consumer-lane direct loads (r6-verified map)
    const int* mrowp = mask + (size_t)(bq + qbase + w * 16 + li) * L_;

    const int kbo = lg * 256 + li * 16;  // frag-order read offset (2-way max)

    // QK^T for sub-tile at Ks (frag order) -> a0 (k rows +0..15), a1 (+16..31)
    auto qkt = [&](const char* Ks, f32x4& a0, f32x4& a1) {
        f32x4 r0 = {0.f,0.f,0.f,0.f}, r1 = {0.f,0.f,0.f,0.f};
        #pragma unroll
        for (int ds = 0; ds < 4; ++ds) {
            bf16x8 k0 = *(const bf16x8*)(Ks + ds * 2048 + kbo);
            r0 = MFMA_BF16(k0, aq[ds], r0, 0, 0, 0);
        }
        #pragma unroll
        for (int ds = 0; ds < 4; ++ds) {
            bf16x8 k1 = *(const bf16x8*)(Ks + ds * 2048 + 1024 + kbo);
            r1 = MFMA_BF16(k1, aq[ds], r1, 0, 0, 0);
        }
        a0 = r0; a1 = r1;
    };

    // ================= PASS 1: macro=128, mask in registers ==================
    float m_run = -3.4e38f, l_run = 0.f;
    {
        // K: 4 subs per macro
        auto issueK4 = [&](int t, i32x4 (&ri)[4], f32x4 (&rf)[4][2]) {
            #pragma unroll
            for (int s = 0; s < 4; ++s) {
                if constexpr (WS) {
                    ri[s] = *(const i32x4*)(ksrcb + (size_t)(t * 128 + s * 32) * D_);
                } else {
                    rf[s][0] = *(const f32x4*)(ksrcf + (size_t)(t * 128 + s * 32) * D_);
                    rf[s][1] = *(const f32x4*)(ksrcf + (size_t)(t * 128 + s * 32) * D_ + 4);
                }
            }
        };
        auto writeK4 = [&](int sl, const i32x4 (&ri)[4], const f32x4 (&rf)[4][2]) {
            #pragma unroll
            for (int s = 0; s < 4; ++s) {
                char* d = Kbig + sl * 32768 + s * 8192 + tid * 16;
                if constexpr (WS) {
                    *(i32x4*)d = ri[s];
                } else {
                    bf16x8 o;
                    #pragma unroll
                    for (int u = 0; u < 4; ++u) { o[u] = (bf16_t)rf[s][0][u]; o[4+u] = (bf16_t)rf[s][1][u]; }
                    *(bf16x8*)d = o;
                }
            }
        };
        // mask: 4 subs per macro, per-lane own row
        auto issueM4 = [&](int t, i32x4 (&ma)[4], i32x4 (&mb)[4]) {
            #pragma unroll
            for (int s = 0; s < 4; ++s) {
                const int c0 = t * 128 + s * 32;
                ma[s] = __builtin_nontemporal_load((const i32x4*)(mrowp + c0 + lg * 4));
                mb[s] = __builtin_nontemporal_load((const i32x4*)(mrowp + c0 + 16 + lg * 4));
            }
        };

        unsigned mword = 0;
        auto p1c = [&](int m, const char* Ks, i32x4 va, i32x4 vb_) {
            f32x4 a0, a1;
            qkt(Ks, a0, a1);
            unsigned byte =
                (va[0]  != 0 ?   1u : 0u) | (va[1]  != 0 ?   2u : 0u) |
                (va[2]  != 0 ?   4u : 0u) | (va[3]  != 0 ?   8u : 0u) |
                (vb_[0] != 0 ?  16u : 0u) | (vb_[1] != 0 ?  32u : 0u) |
                (vb_[2] != 0 ?  64u : 0u) | (vb_[3] != 0 ? 128u : 0u);
            float s0[4], s1[4];
            #pragma unroll
            for (int r = 0; r < 4; ++r) {
                s0[r] = a0[r] + (((byte >> r)       & 1u) ? 0.f : NEGINF);
                s1[r] = a1[r] + (((byte >> (4 + r)) & 1u) ? 0.f : NEGINF);
            }
            float mx = fmaxf(fmaxf(fmaxf(s0[0], s0[1]), fmaxf(s0[2], s0[3])),
                             fmaxf(fmaxf(s1[0], s1[1]), fmaxf(s1[2], s1[3])));
            mx = fmaxf(mx, m_run);
            float acc = 0.f;
            #pragma unroll
            for (int r = 0; r < 4; ++r)
                acc += __expf(s0[r] - mx) + __expf(s1[r] - mx);
            l_run = l_run * __expf(m_run - mx) + acc;
            m_run = mx;
            mword |= byte << ((m & 3) * 8);
            if ((m & 3) == 3) { mlds[w * 1024 + (m >> 2) * 64 + l] = mword; mword = 0; }
        };

        i32x4 kA[4]{}, kB[4]{};
        f32x4 kfA[4][2], kfB[4][2];
        i32x4 maA[4]{}, mbA[4]{}, maB[4]{}, mbB[4]{};

        issueK4(0, kA, kfA); issueM4(0, maA, mbA);
        issueK4(1, kB, kfB); issueM4(1, maB, mbB);
        writeK4(0, kA, kfA);
        BARRIER();
        #pragma unroll 1
        for (int t = 0; t < 16; t += 2) {
            // macro t (even, slab 0), mask set A
            if (t + 2 < 16) issueK4(t + 2, kA, kfA);
            p1c(4 * t + 0, Kbig + 0 * 8192, maA[0], mbA[0]);
            p1c(4 * t + 1, Kbig + 1 * 8192, maA[1], mbA[1]);
            p1c(4 * t + 2, Kbig + 2 * 8192, maA[2], mbA[2]);
            p1c(4 * t + 3, Kbig + 3 * 8192, maA[3], mbA[3]);
            if (t + 2 < 16) issueM4(t + 2, maA, mbA);
            writeK4(1, kB, kfB);                 // macro t+1 -> slab 1
            BARRIER();
            // macro t+1 (odd, slab 1), mask set B
            if (t + 3 < 16) issueK4(t + 3, kB, kfB);
            p1c(4 * t + 4, Kbig + 32768 + 0 * 8192, maB[0], mbB[0]);
            p1c(4 * t + 5, Kbig + 32768 + 1 * 8192, maB[1], mbB[1]);
            p1c(4 * t + 6, Kbig + 32768 + 2 * 8192, maB[2], mbB[2]);
            p1c(4 * t + 7, Kbig + 32768 + 3 * 8192, maB[3], mbB[3]);
            if (t + 3 < 16) issueM4(t + 3, maB, mbB);
            if (t + 2 < 16) writeK4(0, kA, kfA); // macro t+2 -> slab 0
            BARRIER();
        }
    }

    // merge m/sum across the 4 lane-groups (lanes li, li+16, li+32, li+48)
    #pragma unroll
    for (int off = 16; off < 64; off <<= 1) {
        float mo = __shfl_xor(m_run, off);
        float lo = __shfl_xor(l_run, off);
        float mn = fmaxf(m_run, mo);
        l_run = l_run * __expf(m_run - mn) + lo * __expf(mo - mn);
        m_run = mn;
    }
    const float inv_l = 1.f / l_run;

    // ================= PASS 2: r15 verbatim (macro=64), re-based slabs ======
    f32x4 pv[8];
    #pragma unroll
    for (int dt = 0; dt < 8; ++dt) pv[dt] = {0.f, 0.f, 0.f, 0.f};

    {
        auto issueK = [&](int t, i32x4 (&ri)[2], f32x4 (&rf)[2][2]) {
            #pragma unroll
            for (int s = 0; s < 2; ++s) {
                if constexpr (WS) {
                    ri[s] = *(const i32x4*)(ksrcb + (size_t)(t * 64 + s * 32) * D_);
                } else {
                    rf[s][0] = *(const f32x4*)(ksrcf + (size_t)(t * 64 + s * 32) * D_);
                    rf[s][1] = *(const f32x4*)(ksrcf + (size_t)(t * 64 + s * 32) * D_ + 4);
                }
            }
        };
        auto writeK = [&](int sl, const i32x4 (&ri)[2], const f32x4 (&rf)[2][2]) {
            #pragma unroll
            for (int s = 0; s < 2; ++s) {
                char* d = Kbig + sl * 16384 + s * 8192 + tid * 16;
                if constexpr (WS) {
                    *(i32x4*)d = ri[s];
                } else {
                    bf16x8 o;
                    #pragma unroll
                    for (int u = 0; u < 4; ++u) { o[u] = (bf16_t)rf[s][0][u]; o[4+u] = (bf16_t)rf[s][1][u]; }
                    *(bf16x8*)d = o;
                }
            }
        };
        auto issueV = [&](int t, i32x4 (&ri)[2], float (&vf)[2][8]) {
            #pragma unroll
            for (int s = 0; s < 2; ++s) {
                if constexpr (WS) {
                    ri[s] = *(const i32x4*)(vsrcb + t * 64 + s * 32);
                } else {
                    #pragma unroll
                    for (int u = 0; u < 8; ++u)
                        vf[s][u] = vp[(size_t)(t * 64 + s * 32 + vu_lg * 8 + u) * D_ + vu_d];
                }
            }
        };
        auto writeV = [&](int sl, const i32x4 (&ri)[2], const float (&vf)[2][8]) {
            #pragma unroll
            for (int s = 0; s < 2; ++s) {
                char* d = Vbuf + sl * 16384 + s * 8192 + tid * 16;
                if constexpr (WS) {
                    *(i32x4*)d = ri[s];
                } else {
                    bf16x8 o;
                    #pragma unroll
                    for (int u = 0; u < 8; ++u) o[u] = (bf16_t)vf[s][u];
                    *(bf16x8*)d = o;
                }
            }
        };

        auto p2c = [&](int m, int sl, int s) {
            f32x4 a0, a1;
            qkt(Kbig + sl * 16384 + s * 8192, a0, a1);
            const unsigned mw = mlds[w * 1024 + (m >> 2) * 64 + l];
            const unsigned byte = (mw >> ((m & 3) * 8)) & 0xffu;
            f32x4 o0, o1; bf16x4 pb0, pb1;
            #pragma unroll
            for (int r = 0; r < 4; ++r) {
                float sa = a0[r] + (((byte >> r)       & 1u) ? 0.f : NEGINF);
                float sb = a1[r] + (((byte >> (4 + r)) & 1u) ? 0.f : NEGINF);
                float p0 = __expf(sa - m_run);
                float p1 = __expf(sb - m_run);
                o0[r] = p0 * inv_l;  o1[r] = p1 * inv_l;
                pb0[r] = (bf16_t)p0; pb1[r] = (bf16_t)p1;
            }
            __builtin_nontemporal_store(o0, (f32x4*)(attnrow + m * 32 + lg * 4));
            __builtin_nontemporal_store(o1, (f32x4*)(attnrow + m * 32 + 16 + lg * 4));
            *(bf16x4*)&plds[w][li][lg * 4]      = pb0;
            *(bf16x4*)&plds[w][li][16 + lg * 4] = pb1;
            bf16x8 pa = *(const bf16x8*)&plds[w][li][lg * 8];
            const char* Vs = Vbuf + sl * 16384 + s * 8192;
            #pragma unroll
            for (int dt = 0; dt < 8; ++dt) {
                bf16x8 vbf = *(const bf16x8*)(Vs + dt * 1024 + kbo);
                pv[dt] = MFMA_BF16(pa, vbf, pv[dt], 0, 0, 0);
            }
        };

        i32x4 kA[2]{}, kB[2]{}, vA[2]{}, vB[2]{};
        f32x4 kfA[2][2], kfB[2][2];
        float vfA[2][8], vfB[2][8];
        issueK(0, kA, kfA); issueV(0, vA, vfA);
        issueK(1, kB, kfB); issueV(1, vB, vfB);
        writeK(0, kA, kfA); writeV(0, vA, vfA);
        BARRIER();
        #pragma unroll 1
        for (int t = 0; t < 32; t += 2) {
            // macro t (even, slab 0)
            if (t + 2 < 32) { issueK(t + 2, kA, kfA); issueV(t + 2, vA, vfA); }
            p2c(2 * t,     0, 0);
            p2c(2 * t + 1, 0, 1);
            writeK(1, kB, kfB); writeV(1, vB, vfB);      // chunk t+1 -> slab 1
            BARRIER();
            // macro t+1 (odd, slab 1)
            if (t + 3 < 32) { issueK(t + 3, kB, kfB); issueV(t + 3, vB, vfB); }
            p2c(2 * t + 2, 1, 0);
            p2c(2 * t + 3, 1, 1);
            if (t + 2 < 32) { writeK(0, kA, kfA); writeV(0, vA, vfA); }   // chunk t+2 -> slab 0
            BARRIER();
        }
    }

    // ---------------- Epilogue: out[q][d] = pv * inv_l[q]
    #pragma unroll
    for (int r = 0; r < 4; ++r) {
        const float il = __shfl(inv_l, lg * 4 + r);
        float* orow = outp + (size_t)(w * 16 + lg * 4 + r) * D_ + li;
        #pragma unroll
        for (int dt = 0; dt < 8; ++dt)
            __builtin_nontemporal_store(pv[dt][r] * il, orow + dt * 16);
    }
}

extern "C" void kernel_launch(void* const* d_in, const int* in_sizes, int n_in,
                              void* d_out, int out_size, void* d_ws, size_t ws_size,
                              hipStream_t stream) {
    const float* q    = (const float*)d_in[0];
    const float* k    = (const float*)d_in[1];
    const float* v    = (const float*)d_in[2];
    const int*   mask = (const int*)d_in[3];

    float* out  = (float*)d_out;
    float* attn = out + (size_t)B_ * L_ * D_;

    const size_t VT_BYTES = (size_t)B_ * D_ * L_ * 2;   // 8 MB
    const size_t KB_BYTES = (size_t)B_ * L_ * D_ * 2;   // 8 MB
    const bool ws_ok = ws_size >= VT_BYTES + KB_BYTES;
    bf16_t* vt = (bf16_t*)d_ws;
    bf16_t* kb = (bf16_t*)((char*)d_ws + VT_BYTES);

    if (ws_ok) {
        hipLaunchKernelGGL(prep_kernel, dim3(512), dim3(256), 0, stream, k, v, kb, vt);
        hipLaunchKernelGGL(sdpa_kernel<true>, dim3(256), dim3(512), 0, stream,
                           q, k, v, mask, kb, vt, out, attn);
    } else {
        hipLaunchKernelGGL(sdpa_kernel<false>, dim3(256), dim3(512), 0, stream,
                           q, k, v, mask, kb, vt, out, attn);
    }
}

// Round 17
// 172.060 us; speedup vs baseline: 1.0707x; 1.0707x over previous
//
#include <hip/hip_runtime.h>

typedef __bf16 bf16_t;
typedef __bf16 bf16x8 __attribute__((ext_vector_type(8)));
typedef __bf16 bf16x4 __attribute__((ext_vector_type(4)));
typedef float  f32x4  __attribute__((ext_vector_type(4)));
typedef int    i32x4  __attribute__((ext_vector_type(4)));

#define B_      16
#define L_      2048
#define D_      128
#define QTB     128              // q rows per block = 8 waves x 16
#define NEGINF  (-1.0e9f)
#define SCALE   0.08838834764831845f   // 1/sqrt(128)

#define MFMA_BF16 __builtin_amdgcn_mfma_f32_16x16x32_bf16

// Drain LDS ops before the barrier WITHOUT draining vmcnt: global loads for
// future chunks (and NT attn stores) stay in flight across the barrier.
#define BARRIER() do { asm volatile("s_waitcnt lgkmcnt(0)" ::: "memory"); \
                       __builtin_amdgcn_s_barrier(); } while (0)

// ---------------------------------------------------------------------------
// Prep kernel: blocks 0..255  : V fp32 [B][L][D] -> bf16 VT [B][D][L]
//              blocks 256..511: K fp32 -> bf16 row-major
// ---------------------------------------------------------------------------
__global__ __launch_bounds__(256) void prep_kernel(
    const float* __restrict__ k, const float* __restrict__ v,
    bf16_t* __restrict__ kb, bf16_t* __restrict__ vt)
{
    __shared__ bf16_t tile[128 * 144];
    const int tid = threadIdx.x;
    const int bid = (int)blockIdx.x;

    if (bid < 256) {
        const int b  = bid >> 4;
        const int l0 = (bid & 15) * 128;
        #pragma unroll
        for (int it = 0; it < 16; ++it) {
            int idx = tid + it * 256;
            int row = idx >> 5;
            int dc4 = idx & 31;
            f32x4 x = __builtin_nontemporal_load(
                (const f32x4*)(v + ((size_t)b * L_ + l0 + row) * (size_t)D_ + dc4 * 4));
            #pragma unroll
            for (int i = 0; i < 4; ++i) tile[(dc4 * 4 + i) * 144 + row] = (bf16_t)x[i];
        }
        __syncthreads();
        #pragma unroll
        for (int it = 0; it < 8; ++it) {
            int idx = tid + it * 256;
            int d   = idx >> 4;
            int lc  = idx & 15;
            bf16x8 vec = *(const bf16x8*)&tile[d * 144 + lc * 8];
            *(bf16x8*)(vt + ((size_t)b * D_ + d) * (size_t)L_ + l0 + lc * 8) = vec;
        }
    } else {
        const int idx0 = (bid - 256) * 256 + tid;
        #pragma unroll
        for (int c = 0; c < 16; ++c) {
            int idx = idx0 + c * 65536;
            f32x4 x = __builtin_nontemporal_load((const f32x4*)(k + (size_t)idx * 4));
            bf16x4 o;
            #pragma unroll
            for (int i = 0; i < 4; ++i) o[i] = (bf16_t)x[i];
            *(bf16x4*)(kb + (size_t)idx * 4) = o;
        }
    }
}

// ---------------------------------------------------------------------------
// Main kernel: 256 blocks (1/CU), 8 waves, 128 q-rows per block.
// r13/r14 structure (macro-chunk = 64 k-cols, 2-slab double buffer, ONE
// barrier per macro-chunk, frag-order K/V slabs) + DISTANCE-2 register
// pipeline: chunk t+2 issued at iteration t (A/B reg sets by parity), so the
// ds_write's vmcnt wait covers a full iteration (~6000cy >> HBM latency).
// ---------------------------------------------------------------------------
template <bool WS>
__global__ __launch_bounds__(512, 1) void sdpa_kernel(
    const float* __restrict__ q, const float* __restrict__ k,
    const float* __restrict__ v, const int* __restrict__ mask,
    const bf16_t* __restrict__ kb, const bf16_t* __restrict__ vt,
    float* __restrict__ out, float* __restrict__ attn)
{
    __shared__ char     Kst[2][16384];     // 32KB: 2 slabs x 2 sub-tiles, frag order
    __shared__ char     MV[2][32768];      // 64KB: p1 mask 2x16K subs; p2 V 2x8K subs (frag)
    __shared__ unsigned mlds[8 * 1024];    // 32KB packed mask bits (per-wave regions)
    __shared__ bf16_t   plds[8][16][40];   // 10KB P bounce (per-wave)

    const int tid = threadIdx.x;
    const int w   = tid >> 6;
    const int l   = tid & 63;
    const int li  = l & 15;
    const int lg  = l >> 4;

    // XCD-chunked bijective swizzle (256 % 8 == 0): 2 whole batches per XCD
    const int bid  = (int)blockIdx.x;
    const int bid2 = (bid & 7) * 32 + (bid >> 3);
    const int b    = bid2 >> 4;
    const int qt   = bid2 & 15;
    const int qbase = qt * QTB;

    const size_t bq = (size_t)b * L_;

    const float*  qp  = q  + (bq + qbase) * (size_t)D_;
    const bf16_t* kbp = kb + bq * (size_t)D_;
    const float*  kp  = k  + bq * (size_t)D_;
    const bf16_t* vtp = vt + (size_t)b * D_ * (size_t)L_;
    const float*  vp  = v  + bq * (size_t)D_;
    float* attnrow = attn + (bq + qbase + (size_t)(w * 16 + li)) * (size_t)L_;
    float* outp    = out  + (bq + qbase) * (size_t)D_;

    // ---------------- Q B-fragments (pre-scaled by 1/temper)
    bf16x8 aq[4];
    #pragma unroll
    for (int ds = 0; ds < 4; ++ds) {
        const float* p = qp + (size_t)(w * 16 + li) * D_ + ds * 32 + lg * 8;
        f32x4 x0 = *(const f32x4*)p;
        f32x4 x1 = *(const f32x4*)(p + 4);
        bf16x8 a;
        #pragma unroll
        for (int u = 0; u < 4; ++u) {
            a[u]     = (bf16_t)(x0[u] * SCALE);
            a[4 + u] = (bf16_t)(x1[u] * SCALE);
        }
        aq[ds] = a;
    }

    // ---------------- K staging: fragment order, identity unit (LDS at tid*16)
    const int ku_t  = (tid >> 6) & 1;
    const int ku_lg = (tid >> 4) & 3;
    const int ku_li = tid & 15;
    const int ku_ds = tid >> 7;
    const bf16_t* ksrcb = kbp + (size_t)(ku_t * 16 + ku_li) * D_ + ku_ds * 32 + ku_lg * 8;
    const float*  ksrcf = kp  + (size_t)(ku_t * 16 + ku_li) * D_ + ku_ds * 32 + ku_lg * 8;

    // ---------------- V staging: fragment order, identity unit
    const int vu_d  = ((tid >> 6) << 4) | (tid & 15);
    const int vu_lg = (tid >> 4) & 3;
    const bf16_t* vsrcb = vtp + (size_t)vu_d * L_ + vu_lg * 8;

    // mask: coalesced map — [128 rows][128B]/sub, XOR-swz, rows mrow,mrow+64
    const int mrow = tid >> 3, mslot = tid & 7;
    const int mdst0 = mrow * 128 + ((mslot * 16) ^ ((mrow & 7) << 4));
    const int mdst1 = (mrow + 64) * 128 + ((mslot * 16) ^ ((mrow & 7) << 4));
    const int*    msrc0 = mask + (size_t)(bq + qbase + mrow) * L_ + mslot * 4;
    const int*    msrc1 = mask + (size_t)(bq + qbase + mrow + 64) * L_ + mslot * 4;

    // macro-chunk t covers k-cols [t*64, t*64+64); sub s covers +s*32.
    auto issueK = [&](int t, i32x4 (&ri)[2], f32x4 (&rf)[2][2]) {
        #pragma unroll
        for (int s = 0; s < 2; ++s) {
            if constexpr (WS) {
                ri[s] = *(const i32x4*)(ksrcb + (size_t)(t * 64 + s * 32) * D_);
            } else {
                rf[s][0] = *(const f32x4*)(ksrcf + (size_t)(t * 64 + s * 32) * D_);
                rf[s][1] = *(const f32x4*)(ksrcf + (size_t)(t * 64 + s * 32) * D_ + 4);
            }
        }
    };
    auto writeK = [&](int sl, const i32x4 (&ri)[2], const f32x4 (&rf)[2][2]) {
        #pragma unroll
        for (int s = 0; s < 2; ++s) {
            char* d = Kst[sl] + s * 8192 + tid * 16;
            if constexpr (WS) {
                *(i32x4*)d = ri[s];
            } else {
                bf16x8 o;
                #pragma unroll
                for (int u = 0; u < 4; ++u) { o[u] = (bf16_t)rf[s][0][u]; o[4+u] = (bf16_t)rf[s][1][u]; }
                *(bf16x8*)d = o;
            }
        }
    };
    auto issueM = [&](int t, i32x4 (&m0)[2], i32x4 (&m1)[2]) {
        #pragma unroll
        for (int s = 0; s < 2; ++s) {
            m0[s] = __builtin_nontemporal_load((const i32x4*)(msrc0 + t * 64 + s * 32));
            m1[s] = __builtin_nontemporal_load((const i32x4*)(msrc1 + t * 64 + s * 32));
        }
    };
    auto writeM = [&](int sl, const i32x4 (&m0)[2], const i32x4 (&m1)[2]) {
        #pragma unroll
        for (int s = 0; s < 2; ++s) {
            *(i32x4*)(MV[sl] + s * 16384 + mdst0) = m0[s];
            *(i32x4*)(MV[sl] + s * 16384 + mdst1) = m1[s];
        }
    };
    auto issueV = [&](int t, i32x4 (&ri)[2], float (&vf)[2][8]) {
        #pragma unroll
        for (int s = 0; s < 2; ++s) {
            if constexpr (WS) {
                ri[s] = *(const i32x4*)(vsrcb + t * 64 + s * 32);
            } else {
                #pragma unroll
                for (int u = 0; u < 8; ++u)
                    vf[s][u] = vp[(size_t)(t * 64 + s * 32 + vu_lg * 8 + u) * D_ + vu_d];
            }
        }
    };
    auto writeV = [&](int sl, const i32x4 (&ri)[2], const float (&vf)[2][8]) {
        #pragma unroll
        for (int s = 0; s < 2; ++s) {
            char* d = MV[sl] + s * 8192 + tid * 16;
            if constexpr (WS) {
                *(i32x4*)d = ri[s];
            } else {
                bf16x8 o;
                #pragma unroll
                for (int u = 0; u < 8; ++u) o[u] = (bf16_t)vf[s][u];
                *(bf16x8*)d = o;
            }
        }
    };

    const int xr = (li & 7) << 4;        // mask-slab read-side XOR
    const int kbo = lg * 256 + li * 16;  // frag-order read offset (2-way max)

    // QK^T for sub-tile at Ks (frag order) -> a0 (k rows +0..15), a1 (+16..31)
    auto qkt = [&](const char* Ks, f32x4& a0, f32x4& a1) {
        f32x4 r0 = {0.f,0.f,0.f,0.f}, r1 = {0.f,0.f,0.f,0.f};
        #pragma unroll
        for (int ds = 0; ds < 4; ++ds) {
            bf16x8 k0 = *(const bf16x8*)(Ks + ds * 2048 + kbo);
            r0 = MFMA_BF16(k0, aq[ds], r0, 0, 0, 0);
        }
        #pragma unroll
        for (int ds = 0; ds < 4; ++ds) {
            bf16x8 k1 = *(const bf16x8*)(Ks + ds * 2048 + 1024 + kbo);
            r1 = MFMA_BF16(k1, aq[ds], r1, 0, 0, 0);
        }
        a0 = r0; a1 = r1;
    };

    // ================= PASS 1: online masked max/sum ========================
    float m_run = -3.4e38f, l_run = 0.f;
    {
        unsigned mword = 0;
        auto p1c = [&](int m, int sl, int s) {
            f32x4 a0, a1;
            qkt(Kst[sl] + s * 8192, a0, a1);
            const char* Ms = MV[sl] + s * 16384 + (w * 16 + li) * 128;
            i32x4 va  = *(const i32x4*)(Ms + ((lg * 16) ^ xr));
            i32x4 vb_ = *(const i32x4*)(Ms + ((64 + lg * 16) ^ xr));
            unsigned byte =
                (va[0]  != 0 ?   1u : 0u) | (va[1]  != 0 ?   2u : 0u) |
                (va[2]  != 0 ?   4u : 0u) | (va[3]  != 0 ?   8u : 0u) |
                (vb_[0] != 0 ?  16u : 0u) | (vb_[1] != 0 ?  32u : 0u) |
                (vb_[2] != 0 ?  64u : 0u) | (vb_[3] != 0 ? 128u : 0u);
            float s0[4], s1[4];
            #pragma unroll
            for (int r = 0; r < 4; ++r) {
                s0[r] = a0[r] + (((byte >> r)       & 1u) ? 0.f : NEGINF);
                s1[r] = a1[r] + (((byte >> (4 + r)) & 1u) ? 0.f : NEGINF);
            }
            float mx = fmaxf(fmaxf(fmaxf(s0[0], s0[1]), fmaxf(s0[2], s0[3])),
                             fmaxf(fmaxf(s1[0], s1[1]), fmaxf(s1[2], s1[3])));
            mx = fmaxf(mx, m_run);
            float acc = 0.f;
            #pragma unroll
            for (int r = 0; r < 4; ++r)
                acc += __expf(s0[r] - mx) + __expf(s1[r] - mx);
            l_run = l_run * __expf(m_run - mx) + acc;
            m_run = mx;
            mword |= byte << ((m & 3) * 8);
            if ((m & 3) == 3) { mlds[w * 1024 + (m >> 2) * 64 + l] = mword; mword = 0; }
        };

        // A = even macro-chunks, B = odd macro-chunks (static set selection)
        i32x4 kA[2]{}, kB[2]{}, m0A[2]{}, m1A[2]{}, m0B[2]{}, m1B[2]{};
        f32x4 kfA[2][2], kfB[2][2];
        issueK(0, kA, kfA); issueM(0, m0A, m1A);
        issueK(1, kB, kfB); issueM(1, m0B, m1B);
        writeK(0, kA, kfA); writeM(0, m0A, m1A);
        BARRIER();
        #pragma unroll 1
        for (int t = 0; t < 32; t += 2) {
            // macro t (even, slab 0)
            if (t + 2 < 32) { issueK(t + 2, kA, kfA); issueM(t + 2, m0A, m1A); }
            p1c(2 * t,     0, 0);
            p1c(2 * t + 1, 0, 1);
            writeK(1, kB, kfB); writeM(1, m0B, m1B);     // chunk t+1 -> slab 1
            BARRIER();
            // macro t+1 (odd, slab 1)
            if (t + 3 < 32) { issueK(t + 3, kB, kfB); issueM(t + 3, m0B, m1B); }
            p1c(2 * t + 2, 1, 0);
            p1c(2 * t + 3, 1, 1);
            if (t + 2 < 32) { writeK(0, kA, kfA); writeM(0, m0A, m1A); }  // chunk t+2 -> slab 0
            BARRIER();
        }
    }

    // merge m/sum across the 4 lane-groups (lanes li, li+16, li+32, li+48)
    #pragma unroll
    for (int off = 16; off < 64; off <<= 1) {
        float mo = __shfl_xor(m_run, off);
        float lo = __shfl_xor(l_run, off);
        float mn = fmaxf(m_run, mo);
        l_run = l_run * __expf(m_run - mn) + lo * __expf(mo - mn);
        m_run = mn;
    }
    const float inv_l = 1.f / l_run;

    // ================= PASS 2: recompute + attn write + PV ==================
    f32x4 pv[8];
    #pragma unroll
    for (int dt = 0; dt < 8; ++dt) pv[dt] = {0.f, 0.f, 0.f, 0.f};

    {
        auto p2c = [&](int m, int sl, int s) {
            f32x4 a0, a1;
            qkt(Kst[sl] + s * 8192, a0, a1);
            const unsigned mw = mlds[w * 1024 + (m >> 2) * 64 + l];
            const unsigned byte = (mw >> ((m & 3) * 8)) & 0xffu;
            f32x4 o0, o1; bf16x4 pb0, pb1;
            #pragma unroll
            for (int r = 0; r < 4; ++r) {
                float sa = a0[r] + (((byte >> r)       & 1u) ? 0.f : NEGINF);
                float sb = a1[r] + (((byte >> (4 + r)) & 1u) ? 0.f : NEGINF);
                float p0 = __expf(sa - m_run);
                float p1 = __expf(sb - m_run);
                o0[r] = p0 * inv_l;  o1[r] = p1 * inv_l;
                pb0[r] = (bf16_t)p0; pb1[r] = (bf16_t)p1;
            }
            __builtin_nontemporal_store(o0, (f32x4*)(attnrow + m * 32 + lg * 4));
            __builtin_nontemporal_store(o1, (f32x4*)(attnrow + m * 32 + 16 + lg * 4));
            *(bf16x4*)&plds[w][li][lg * 4]      = pb0;
            *(bf16x4*)&plds[w][li][16 + lg * 4] = pb1;
            bf16x8 pa = *(const bf16x8*)&plds[w][li][lg * 8];
            const char* Vs = MV[sl] + s * 8192;
            #pragma unroll
            for (int dt = 0; dt < 8; ++dt) {
                bf16x8 vbf = *(const bf16x8*)(Vs + dt * 1024 + kbo);
                pv[dt] = MFMA_BF16(pa, vbf, pv[dt], 0, 0, 0);
            }
        };

        i32x4 kA[2]{}, kB[2]{}, vA[2]{}, vB[2]{};
        f32x4 kfA[2][2], kfB[2][2];
        float vfA[2][8], vfB[2][8];
        issueK(0, kA, kfA); issueV(0, vA, vfA);
        issueK(1, kB, kfB); issueV(1, vB, vfB);
        writeK(0, kA, kfA); writeV(0, vA, vfA);
        BARRIER();
        #pragma unroll 1
        for (int t = 0; t < 32; t += 2) {
            // macro t (even, slab 0)
            if (t + 2 < 32) { issueK(t + 2, kA, kfA); issueV(t + 2, vA, vfA); }
            p2c(2 * t,     0, 0);
            p2c(2 * t + 1, 0, 1);
            writeK(1, kB, kfB); writeV(1, vB, vfB);      // chunk t+1 -> slab 1
            BARRIER();
            // macro t+1 (odd, slab 1)
            if (t + 3 < 32) { issueK(t + 3, kB, kfB); issueV(t + 3, vB, vfB); }
            p2c(2 * t + 2, 1, 0);
            p2c(2 * t + 3, 1, 1);
            if (t + 2 < 32) { writeK(0, kA, kfA); writeV(0, vA, vfA); }   // chunk t+2 -> slab 0
            BARRIER();
        }
    }

    // ---------------- Epilogue: out[q][d] = pv * inv_l[q]
    #pragma unroll
    for (int r = 0; r < 4; ++r) {
        const float il = __shfl(inv_l, lg * 4 + r);
        float* orow = outp + (size_t)(w * 16 + lg * 4 + r) * D_ + li;
        #pragma unroll
        for (int dt = 0; dt < 8; ++dt)
            __builtin_nontemporal_store(pv[dt][r] * il, orow + dt * 16);
    }
}

extern "C" void kernel_launch(void* const* d_in, const int* in_sizes, int n_in,
                              void* d_out, int out_size, void* d_ws, size_t ws_size,
                              hipStream_t stream) {
    const float* q    = (const float*)d_in[0];
    const float* k    = (const float*)d_in[1];
    const float* v    = (const float*)d_in[2];
    const int*   mask = (const int*)d_in[3];

    float* out  = (float*)d_out;
    float* attn = out + (size_t)B_ * L_ * D_;

    const size_t VT_BYTES = (size_t)B_ * D_ * L_ * 2;   // 8 MB
    const size_t KB_BYTES = (size_t)B_ * L_ * D_ * 2;   // 8 MB
    const bool ws_ok = ws_size >= VT_BYTES + KB_BYTES;
    bf16_t* vt = (bf16_t*)d_ws;
    bf16_t* kb = (bf16_t*)((char*)d_ws + VT_BYTES);

    if (ws_ok) {
        hipLaunchKernelGGL(prep_kernel, dim3(512), dim3(256), 0, stream, k, v, kb, vt);
        hipLaunchKernelGGL(sdpa_kernel<true>, dim3(256), dim3(512), 0, stream,
                           q, k, v, mask, kb, vt, out, attn);
    } else {
        hipLaunchKernelGGL(sdpa_kernel<false>, dim3(256), dim3(512), 0, stream,
                           q, k, v, mask, kb, vt, out, attn);
    }
}